// Round 1
// baseline (4563.228 us; speedup 1.0000x reference)
//
#include <hip/hip_runtime.h>
#include <hip/hip_bf16.h>

// LSTM_Net: 2-layer LSTM (B=64,T=256,IN=64,H=768) + softsign MLP head.
// Round 1: correctness-first. Structure:
//   prep:   fp32->bf16 conversions (x/1.5, Wih0, Whh0, Wih1, Whh1), bias sums
//   gemm:   xg0 = xs @ Wih0^T        (bf16 MFMA, x-contribution only)
//   256x:   lstm_step layer0 (gates = xg + bias + h@Whh^T via MFMA, pointwise)
//   gemm:   xg1 = h1 @ Wih1^T        (aliases xg0 buffer)
//   256x:   lstm_step layer1
//   head:   z = softsign(h_last@W1^T + b1); out = (z@W2^T + b2)*70
//
// Precision: xg stores ONLY the x-contribution in bf16; combined bias added in
// fp32 in the step kernel (biases dominate gate magnitude). Recurrent term
// h@Whh^T is ~1e-4 vs gates ~6e-3, so bf16 error there is ~3e-7 absolute.

#define B_  64
#define T_  256
#define IN_ 64
#define H_  768
#define G_  3072   // 4*H
#define LU_ 256

typedef __bf16 bf16_t;
typedef bf16_t bf16x8 __attribute__((ext_vector_type(8)));
typedef float  f32x4  __attribute__((ext_vector_type(4)));

__device__ __forceinline__ unsigned short f2bf(float f) {
    union { float f; unsigned u; } v; v.f = f;
    unsigned r = v.u + 0x7FFFu + ((v.u >> 16) & 1u);
    return (unsigned short)(r >> 16);
}
__device__ __forceinline__ float bf2f(unsigned short u) {
    union { unsigned u; float f; } v; v.u = ((unsigned)u) << 16;
    return v.f;
}
__device__ __forceinline__ float sigm(float x) {
    return 1.0f / (1.0f + expf(-x));
}

// ---------------- prep: conversions + bias sums ----------------
__global__ __launch_bounds__(256) void prep_kernel(
    const float* __restrict__ x,
    const float* __restrict__ Wih0, const float* __restrict__ Whh0,
    const float* __restrict__ bih0, const float* __restrict__ bhh0,
    const float* __restrict__ Wih1, const float* __restrict__ Whh1,
    const float* __restrict__ bih1, const float* __restrict__ bhh1,
    unsigned short* __restrict__ xs,
    unsigned short* __restrict__ wih0b, unsigned short* __restrict__ whh0b,
    unsigned short* __restrict__ wih1b, unsigned short* __restrict__ whh1b,
    float* __restrict__ bias0, float* __restrict__ bias1)
{
    int i = blockIdx.x * blockDim.x + threadIdx.x;
    int stride = gridDim.x * blockDim.x;
    const int NX  = B_ * T_ * IN_;   // 1048576
    const int NW0 = G_ * IN_;        // 196608
    const int NW  = G_ * H_;         // 2359296
    for (int j = i; j < NX;  j += stride) xs[j]    = f2bf(x[j] * (1.0f / 1.5f));
    for (int j = i; j < NW0; j += stride) wih0b[j] = f2bf(Wih0[j]);
    for (int j = i; j < NW;  j += stride) whh0b[j] = f2bf(Whh0[j]);
    for (int j = i; j < NW;  j += stride) wih1b[j] = f2bf(Whh1 ? Wih1[j] : 0.f);
    for (int j = i; j < NW;  j += stride) whh1b[j] = f2bf(Whh1[j]);
    for (int j = i; j < G_;  j += stride) { bias0[j] = bih0[j] + bhh0[j];
                                            bias1[j] = bih1[j] + bhh1[j]; }
}

// ---------------- generic bf16 GEMM: C[M,N] = A[M,K] @ Bw[N,K]^T -------------
// Block = 256 thr (4 waves, 2x2), block tile 64(M) x 128(N), wave tile 32x64.
// Direct global loads (no LDS): relies on L2 (Bw fits aggregate L2).
__global__ __launch_bounds__(256) void gemm_bf16_kernel(
    const unsigned short* __restrict__ A,
    const unsigned short* __restrict__ Bw,
    unsigned short* __restrict__ C,
    int K, int N)
{
    int lane = threadIdx.x & 63;
    int wave = threadIdx.x >> 6;
    int wm = wave >> 1, wn = wave & 1;
    int m0 = blockIdx.y * 64  + wm * 32;
    int n0 = blockIdx.x * 128 + wn * 64;
    int frow = lane & 15;
    int kof  = (lane >> 4) * 8;

    f32x4 acc[2][4] = {};
    for (int kk = 0; kk < K; kk += 32) {
        bf16x8 a[2], b[4];
        #pragma unroll
        for (int mi = 0; mi < 2; mi++)
            a[mi] = *reinterpret_cast<const bf16x8*>(
                A + (size_t)(m0 + mi * 16 + frow) * K + kk + kof);
        #pragma unroll
        for (int ni = 0; ni < 4; ni++)
            b[ni] = *reinterpret_cast<const bf16x8*>(
                Bw + (size_t)(n0 + ni * 16 + frow) * K + kk + kof);
        #pragma unroll
        for (int mi = 0; mi < 2; mi++)
            #pragma unroll
            for (int ni = 0; ni < 4; ni++)
                acc[mi][ni] = __builtin_amdgcn_mfma_f32_16x16x32_bf16(
                    a[mi], b[ni], acc[mi][ni], 0, 0, 0);
    }
    int crow0 = (lane >> 4) * 4;
    int ccol  = lane & 15;
    #pragma unroll
    for (int mi = 0; mi < 2; mi++)
        #pragma unroll
        for (int ni = 0; ni < 4; ni++)
            #pragma unroll
            for (int i = 0; i < 4; i++) {
                int r = m0 + mi * 16 + crow0 + i;
                int c = n0 + ni * 16 + ccol;
                C[(size_t)r * N + c] = f2bf(acc[mi][ni][i]);
            }
}

// ---------------- LSTM step: gates = xg + bias + h_in @ Whh^T ---------------
// Grid (48, 4) x 64 thr: blockIdx.x = 16-col h tile, blockIdx.y = 16-row batch
// tile. Each wave computes the 4 gate tiles (i,f,g,o) for its 16x16 patch,
// then the pointwise c/h update. h double-buffered across steps (h_in/h_out)
// because blocks of one launch are unordered.
__global__ __launch_bounds__(64) void lstm_step_kernel(
    const unsigned short* __restrict__ xg,    // [B*T, 3072] bf16 (x-part only)
    const unsigned short* __restrict__ Whhb,  // [3072, 768] bf16
    const float* __restrict__ bias,           // [3072] fp32 (bih+bhh)
    const unsigned short* __restrict__ h_in,  // [64, 768] bf16
    float* __restrict__ cstate,               // [64, 768] fp32 (in-place ok)
    unsigned short* __restrict__ h_out,       // [64, 768] bf16
    float* __restrict__ h_f32,                // [64, 768] fp32 (for head)
    unsigned short* __restrict__ seq_out,     // [B*T, 768] bf16 or nullptr
    int t)
{
    int lane = threadIdx.x & 63;
    int mrow0 = blockIdx.y * 16;      // batch row tile
    int n0    = blockIdx.x * 16;      // h-col tile
    int frow = lane & 15;
    int kof  = (lane >> 4) * 8;

    f32x4 acc[4] = {};                // i, f, g, o
    for (int kk = 0; kk < H_; kk += 32) {
        bf16x8 a = *reinterpret_cast<const bf16x8*>(
            h_in + (size_t)(mrow0 + frow) * H_ + kk + kof);
        #pragma unroll
        for (int q = 0; q < 4; q++) {
            bf16x8 b = *reinterpret_cast<const bf16x8*>(
                Whhb + (size_t)(q * H_ + n0 + frow) * H_ + kk + kof);
            acc[q] = __builtin_amdgcn_mfma_f32_16x16x32_bf16(a, b, acc[q], 0, 0, 0);
        }
    }

    int ccol = n0 + (lane & 15);
    #pragma unroll
    for (int i = 0; i < 4; i++) {
        int brow = mrow0 + (lane >> 4) * 4 + i;
        size_t xbase = ((size_t)brow * T_ + t) * G_;
        float pi = acc[0][i] + bf2f(xg[xbase + 0 * H_ + ccol]) + bias[0 * H_ + ccol];
        float pf = acc[1][i] + bf2f(xg[xbase + 1 * H_ + ccol]) + bias[1 * H_ + ccol];
        float pg = acc[2][i] + bf2f(xg[xbase + 2 * H_ + ccol]) + bias[2 * H_ + ccol];
        float po = acc[3][i] + bf2f(xg[xbase + 3 * H_ + ccol]) + bias[3 * H_ + ccol];
        size_t sidx = (size_t)brow * H_ + ccol;
        float cp = cstate[sidx];
        float cn = sigm(pf) * cp + sigm(pi) * tanhf(pg);
        float hn = sigm(po) * tanhf(cn);
        cstate[sidx] = cn;
        h_out[sidx]  = f2bf(hn);
        h_f32[sidx]  = hn;
        if (seq_out) seq_out[((size_t)brow * T_ + t) * H_ + ccol] = f2bf(hn);
    }
}

// ---------------- head: out[b] = 70*(softsign(h@W1^T + b1)@W2^T + b2) -------
__global__ __launch_bounds__(256) void head_kernel(
    const float* __restrict__ hlast,   // [64, 768]
    const float* __restrict__ W1, const float* __restrict__ b1,
    const float* __restrict__ W2, const float* __restrict__ b2,
    float* __restrict__ out)
{
    __shared__ float hs[H_];
    __shared__ float partial[4];
    int b = blockIdx.x;
    int tid = threadIdx.x;
    for (int j = tid; j < H_; j += 256) hs[j] = hlast[(size_t)b * H_ + j];
    __syncthreads();
    float z = 0.f;
    const float* w = W1 + (size_t)tid * H_;
    for (int j = 0; j < H_; j++) z += hs[j] * w[j];
    z += b1[tid];
    z = z / (1.0f + fabsf(z));          // soft_sign
    float p = z * W2[tid];
    #pragma unroll
    for (int off = 32; off > 0; off >>= 1) p += __shfl_down(p, off, 64);
    if ((tid & 63) == 0) partial[tid >> 6] = p;
    __syncthreads();
    if (tid == 0) {
        float s = partial[0] + partial[1] + partial[2] + partial[3];
        out[b] = (s + b2[0]) * 70.0f;
    }
}

extern "C" void kernel_launch(void* const* d_in, const int* in_sizes, int n_in,
                              void* d_out, int out_size, void* d_ws, size_t ws_size,
                              hipStream_t stream) {
    const float* x    = (const float*)d_in[0];
    const float* Wih0 = (const float*)d_in[1];
    const float* Whh0 = (const float*)d_in[2];
    const float* bih0 = (const float*)d_in[3];
    const float* bhh0 = (const float*)d_in[4];
    const float* Wih1 = (const float*)d_in[5];
    const float* Whh1 = (const float*)d_in[6];
    const float* bih1 = (const float*)d_in[7];
    const float* bhh1 = (const float*)d_in[8];
    const float* W1   = (const float*)d_in[9];
    const float* b1   = (const float*)d_in[10];
    const float* W2   = (const float*)d_in[11];
    const float* b2   = (const float*)d_in[12];
    float* out = (float*)d_out;

    // workspace layout (bytes), all 256-aligned. Total ~136.5 MiB.
    char* w = (char*)d_ws;
    unsigned short* xg    = (unsigned short*)w;  w += (size_t)B_*T_*G_*2;   // 100.66 MB (reused for xg1)
    unsigned short* h1s   = (unsigned short*)w;  w += (size_t)B_*T_*H_*2;   // 25.17 MB
    unsigned short* xs    = (unsigned short*)w;  w += (size_t)B_*T_*IN_*2;  // 2.10 MB
    unsigned short* wih0b = (unsigned short*)w;  w += (size_t)G_*IN_*2;     // 0.39 MB
    unsigned short* whh0b = (unsigned short*)w;  w += (size_t)G_*H_*2;      // 4.72 MB
    unsigned short* wih1b = (unsigned short*)w;  w += (size_t)G_*H_*2;
    unsigned short* whh1b = (unsigned short*)w;  w += (size_t)G_*H_*2;
    float* bias0 = (float*)w;  w += G_*4;
    float* bias1 = (float*)w;  w += G_*4;
    char* state_base = w;
    float* cstate = (float*)w;          w += (size_t)B_*H_*4;               // 196608 B
    unsigned short* hbuf0 = (unsigned short*)w; w += (size_t)B_*H_*2;       //  98304 B
    unsigned short* hbuf1 = (unsigned short*)w; w += (size_t)B_*H_*2;       //  98304 B
    size_t state_bytes = (size_t)B_*H_*4 + 2*(size_t)B_*H_*2;
    float* hf32 = (float*)w;            w += (size_t)B_*H_*4;

    // 1. prep
    prep_kernel<<<2048, 256, 0, stream>>>(x, Wih0, Whh0, bih0, bhh0,
                                          Wih1, Whh1, bih1, bhh1,
                                          xs, wih0b, whh0b, wih1b, whh1b,
                                          bias0, bias1);
    // 2. xg0 = xs @ Wih0^T   (M=16384, N=3072, K=64)
    dim3 gg(G_ / 128, (B_ * T_) / 64);
    gemm_bf16_kernel<<<gg, 256, 0, stream>>>(xs, wih0b, xg, IN_, G_);

    // 3. layer 0 recurrence
    hipMemsetAsync(state_base, 0, state_bytes, stream);
    for (int t = 0; t < T_; t++) {
        unsigned short* hin  = (t & 1) ? hbuf1 : hbuf0;
        unsigned short* hout = (t & 1) ? hbuf0 : hbuf1;
        lstm_step_kernel<<<dim3(H_ / 16, B_ / 16), 64, 0, stream>>>(
            xg, whh0b, bias0, hin, cstate, hout, hf32, h1s, t);
    }

    // 4. xg1 = h1 @ Wih1^T   (M=16384, N=3072, K=768), aliases xg buffer
    gemm_bf16_kernel<<<gg, 256, 0, stream>>>(h1s, wih1b, xg, H_, G_);

    // 5. layer 1 recurrence (no sequence output needed)
    hipMemsetAsync(state_base, 0, state_bytes, stream);
    for (int t = 0; t < T_; t++) {
        unsigned short* hin  = (t & 1) ? hbuf1 : hbuf0;
        unsigned short* hout = (t & 1) ? hbuf0 : hbuf1;
        lstm_step_kernel<<<dim3(H_ / 16, B_ / 16), 64, 0, stream>>>(
            xg, whh1b, bias1, hin, cstate, hout, hf32, nullptr, t);
    }

    // 6. head
    head_kernel<<<B_, 256, 0, stream>>>(hf32, W1, b1, W2, b2, out);
}